// Round 7
// baseline (1165.922 us; speedup 1.0000x reference)
//
#include <hip/hip_runtime.h>
#include <hip/hip_bf16.h>

#define N_NODES 512
#define N_EDGES (512 * 512)
#define NBLK 256                 // sort blocks
#define EPB (N_EDGES / NBLK)     // 1024 edges per sort block
#define PADLEN 768               // padded segment length (max cnt ~625)

typedef __attribute__((ext_vector_type(2))) _Float16 half2v;
typedef __attribute__((ext_vector_type(8))) __bf16 bf16x8;
typedef __attribute__((ext_vector_type(16))) float f32x16;
typedef __attribute__((ext_vector_type(2))) float float2v;

#if defined(__has_builtin)
#if __has_builtin(__builtin_amdgcn_fdot2)
#define FDOT2(a, b, c) __builtin_amdgcn_fdot2((a), (b), (c), false)
#endif
#endif
#ifndef FDOT2
static __device__ inline float fdot2_sw(half2v a, half2v b, float c) {
    return (float)a.x * (float)b.x + (float)a.y * (float)b.y + c;
}
#define FDOT2(a, b, c) fdot2_sw((a), (b), (c))
#endif

static __device__ inline unsigned pack_h2(float x, float y) {
    union { _Float16 h[2]; unsigned u; } c;
    c.h[0] = (_Float16)x;
    c.h[1] = (_Float16)y;
    return c.u;
}
static __device__ inline half2v bits_h2(int b) {
    union { int i; half2v h; } c;
    c.i = b;
    return c.h;
}
static __device__ inline unsigned bf16rne(float f) {
    union { float f; unsigned u; } c;
    c.f = f;
    unsigned u = c.u;
    u += 0x7FFFu + ((u >> 16) & 1u);
    return u >> 16;
}
static __device__ inline float bf2f(unsigned h) {
    union { unsigned u; float f; } c;
    c.u = h << 16;
    return c.f;
}

// ---------------------------------------------------------------------------
// Counting sort by dst — no device-scope atomics. agg zeroing folded in.
// ---------------------------------------------------------------------------
__global__ __launch_bounds__(256) void count_kernel(const int* __restrict__ dst,
                                                    int* __restrict__ bcnt,
                                                    float* __restrict__ aggz,
                                                    int aggn) {
    __shared__ int h[N_NODES];
    int tid = threadIdx.x;
    int b = blockIdx.x;
    int gi = b * 256 + tid;
    if (gi < aggn) aggz[gi] = 0.f;
    h[tid] = 0;
    h[tid + 256] = 0;
    __syncthreads();
#pragma unroll
    for (int k = 0; k < EPB / 256; k++)
        atomicAdd(&h[dst[b * EPB + k * 256 + tid]], 1);
    __syncthreads();
    bcnt[b * N_NODES + tid] = h[tid];
    bcnt[b * N_NODES + tid + 256] = h[tid + 256];
}

__global__ __launch_bounds__(512) void scan_kernel(const int* __restrict__ bcnt,
                                                   int* __restrict__ offs,
                                                   int* __restrict__ base) {
    __shared__ int buf[N_NODES];
    int t = threadIdx.x;
    int sum = 0;
#pragma unroll 16
    for (int b = 0; b < NBLK; b++) sum += bcnt[b * N_NODES + t];  // coalesced rows
    buf[t] = sum;
    __syncthreads();
    for (int d = 1; d < N_NODES; d <<= 1) {
        int add = (t >= d) ? buf[t - d] : 0;
        __syncthreads();
        buf[t] += add;
        __syncthreads();
    }
    offs[t + 1] = buf[t];
    if (t == 0) offs[0] = 0;
    int run = buf[t] - sum;  // exclusive global start of bucket t
#pragma unroll 16
    for (int b = 0; b < NBLK; b++) {
        base[b * N_NODES + t] = run;
        run += bcnt[b * N_NODES + t];
    }
}

// scatter: dual-format emit.
//  ed4 (compact, f16 records) for L1/L3 VALU kernels (unchanged consumers)
//  edp (padded @ n*768, 32B bf16 hi/lo records) + srcp for the L2 MFMA kernel
//  A-record k-layout: {eh0..5, 1.0, el0 | el1..el5, 0,0,0}
__global__ __launch_bounds__(256) void scatter_kernel(const int* __restrict__ src,
                                                      const int* __restrict__ dst,
                                                      const float* __restrict__ ea,
                                                      const int* __restrict__ base,
                                                      const int* __restrict__ offs,
                                                      int4* __restrict__ ed4,
                                                      int4* __restrict__ edp,
                                                      int* __restrict__ srcp) {
    __shared__ int lcur[N_NODES];
    __shared__ int loff[N_NODES];
    int tid = threadIdx.x;
    int b = blockIdx.x;
    lcur[tid] = base[b * N_NODES + tid];
    lcur[tid + 256] = base[b * N_NODES + tid + 256];
    loff[tid] = offs[tid];
    loff[tid + 256] = offs[tid + 256];
    __syncthreads();
#pragma unroll
    for (int k = 0; k < EPB / 256; k++) {
        int e = b * EPB + k * 256 + tid;
        const float* a = ea + (size_t)e * 6;
        float a0 = a[0], a1 = a[1], a2 = a[2], a3 = a[3], a4 = a[4], a5 = a[5];
        int dv = dst[e], sv = src[e];
        int p = atomicAdd(&lcur[dv], 1);  // LDS atomic, compact slot
        int4 r;
        r.x = (int)pack_h2(a0, a1);
        r.y = (int)pack_h2(a2, a3);
        r.z = (int)pack_h2(a4, a5);
        r.w = sv;
        ed4[p] = r;
        // padded bf16 record
        int rank = p - loff[dv];
        size_t pi = (size_t)dv * PADLEN + rank;
        unsigned e0 = bf16rne(a0), e1 = bf16rne(a1), e2 = bf16rne(a2);
        unsigned e3 = bf16rne(a3), e4 = bf16rne(a4), e5 = bf16rne(a5);
        unsigned l0 = bf16rne(a0 - bf2f(e0)), l1 = bf16rne(a1 - bf2f(e1));
        unsigned l2 = bf16rne(a2 - bf2f(e2)), l3 = bf16rne(a3 - bf2f(e3));
        unsigned l4 = bf16rne(a4 - bf2f(e4)), l5 = bf16rne(a5 - bf2f(e5));
        int4 r0, r1;
        r0.x = (int)((e1 << 16) | e0);
        r0.y = (int)((e3 << 16) | e2);
        r0.z = (int)((e5 << 16) | e4);
        r0.w = (int)((l0 << 16) | 0x3F80u);  // k6 = 1.0 (bias), k7 = el0
        r1.x = (int)((l2 << 16) | l1);
        r1.y = (int)((l4 << 16) | l3);
        r1.z = (int)l5;
        r1.w = 0;
        edp[pi * 2] = r0;
        edp[pi * 2 + 1] = r1;
        srcp[pi] = sv;
    }
}

// W~ prepack: row j (32B, 16 bf16): {wh0..5, be, wh0 | wh1..5, 0,0,0}
__global__ __launch_bounds__(256) void wprep_kernel(const float* __restrict__ We,
                                                    const float* __restrict__ be,
                                                    int4* __restrict__ wtg) {
    int j = blockIdx.x * 256 + threadIdx.x;
    if (j >= 864) return;
    unsigned w0 = bf16rne(We[0 * 864 + j]), w1 = bf16rne(We[1 * 864 + j]);
    unsigned w2 = bf16rne(We[2 * 864 + j]), w3 = bf16rne(We[3 * 864 + j]);
    unsigned w4 = bf16rne(We[4 * 864 + j]), w5 = bf16rne(We[5 * 864 + j]);
    unsigned bb = bf16rne(be[j]);
    int4 r0, r1;
    r0.x = (int)((w1 << 16) | w0);
    r0.y = (int)((w3 << 16) | w2);
    r0.z = (int)((w5 << 16) | w4);
    r0.w = (int)((w0 << 16) | bb);  // k6 = be, k7 = wh0 (pairs with el0)
    r1.x = (int)((w2 << 16) | w1);
    r1.y = (int)((w4 << 16) | w3);
    r1.z = (int)w5;
    r1.w = 0;
    wtg[j * 2] = r0;
    wtg[j * 2 + 1] = r1;
}

// ---------------------------------------------------------------------------
// Layer-2 edge pipeline via MFMA. One wave per (node, slice g<8); 3 chunks of
// 32 edges. Per chunk: A-frag = direct dwordx4 from 32B record (lane row =
// col, k-half = hi); 27 j-tiles: B-frag b128 from LDS W~, one
// v_mfma_f32_32x32x16_bf16 (C=zc zeros), epilogue: relu + x-scale + 3-slot
// accumulate (o=(col+8t)%24, period 3). x staged per-wave in LDS [40i][32e].
// ---------------------------------------------------------------------------
__global__ __launch_bounds__(256, 3) void nnconv2_mfma(
    const float* __restrict__ h1,    // [512][40] fp32 (pitch 40)
    const char* __restrict__ edp,    // [512*768*32]
    const int* __restrict__ srcp,    // [512*768]
    const int4* __restrict__ wtg,    // [864*2]
    float* __restrict__ agg2)        // [512*24] pre-zeroed
{
    __shared__ int4 wl[1728];          // 27648 B
    __shared__ float xg[4][1280];      // 4 waves x (40i * 32e) = 20480 B
    const int tid = threadIdx.x;
    for (int k = tid; k < 1728; k += 256) wl[k] = wtg[k];
    __syncthreads();

    const int w = (blockIdx.x << 2) + (tid >> 6);  // wave id 0..4095
    const int n = w >> 3, g = w & 7;
    const int lane = tid & 63;
    const int col = lane & 31, hi = lane >> 5;
    float* xw = xg[tid >> 6];

    const char* abase = edp + (size_t)(n * PADLEN + g * 96) * 32 + col * 32 + hi * 16;
    const int* sb = srcp + n * PADLEN + g * 96 + col;
    const char* wbase = (const char*)wl + col * 32 + hi * 16;

    f32x16 zc;
#pragma unroll
    for (int i = 0; i < 16; i++) zc[i] = 0.f;
    float2v ao[3];
#pragma unroll
    for (int s = 0; s < 3; s++) { ao[s].x = 0.f; ao[s].y = 0.f; }

#pragma unroll
    for (int c = 0; c < 3; c++) {
        bf16x8 af = *(const bf16x8*)(abase + c * 1024);
        // stage x[src[e], 0..35] -> xw[i][e] (transposed), 5 float4 passes
#pragma unroll
        for (int p = 0; p < 5; p++) {
            int ig = (p < 4) ? (hi + 2 * p) : (8 + hi);
            int sv = sb[c * 32] & 511;  // mask: pad slots hold poison
            float4 xv = *(const float4*)(h1 + sv * 40 + ig * 4);
            xw[(ig * 4 + 0) * 32 + col] = xv.x;
            xw[(ig * 4 + 1) * 32 + col] = xv.y;
            xw[(ig * 4 + 2) * 32 + col] = xv.z;
            xw[(ig * 4 + 3) * 32 + col] = xv.w;
        }
#pragma unroll
        for (int t = 0; t < 27; t++) {
            bf16x8 bf = *(const bf16x8*)(wbase + t * 1024);
            f32x16 ct = __builtin_amdgcn_mfma_f32_32x32x16_bf16(af, bf, zc, 0, 0, 0);
            int j = t * 32 + col;
            int i = (j * 43691) >> 20;  // j / 24
            const float* xr = xw + i * 32 + hi * 4;
            constexpr int smap[27] = {0,1,2,0,1,2,0,1,2,0,1,2,0,1,2,0,1,2,0,1,2,0,1,2,0,1,2};
            const int s = smap[t];
#pragma unroll
            for (int q = 0; q < 4; q++) {
                float4 xq = *(const float4*)(xr + q * 8);
                float2v z0, x0, z1, x1;
                z0.x = fmaxf(ct[4 * q + 0], 0.f);
                z0.y = fmaxf(ct[4 * q + 1], 0.f);
                x0.x = xq.x; x0.y = xq.y;
                ao[s] += z0 * x0;
                z1.x = fmaxf(ct[4 * q + 2], 0.f);
                z1.y = fmaxf(ct[4 * q + 3], 0.f);
                x1.x = xq.z; x1.y = xq.w;
                ao[s] += z1 * x1;
            }
        }
    }
    // reduce: rows within lane done; fold row-pair + cross half-wave; emit
#pragma unroll
    for (int s = 0; s < 3; s++) {
        float a = ao[s].x + ao[s].y;
        a += __shfl_xor(a, 32);
        if (lane < 32) {
            int o = col + 8 * s;
            if (o >= 24) o -= 24;
            atomicAdd(&agg2[n * 24 + o], a);
        }
    }
}

// ---------------------------------------------------------------------------
// VALU NNConv edge kernel (layers 1 and 3; unchanged from R5 best).
// ---------------------------------------------------------------------------
template <int CIN, int COUT, int OG, int BLK, int G>
__global__ __launch_bounds__(BLK, 4) void nnconv_edges(
    const float* __restrict__ hprev,
    const int4* __restrict__ ed4,
    const int* __restrict__ offs,
    const float* __restrict__ We,
    const float* __restrict__ be,
    float* __restrict__ agg)
{
    constexpr int J = CIN * COUT;
    constexpr int OPL = COUT / OG;
    constexpr int A = CIN * OPL;
    constexpr int U = 16;

    const int n = blockIdx.x / G;
    const int g = blockIdx.x % G;
    const int tid = threadIdx.x;
    const bool act = (tid < A);
    const int i = act ? tid / OPL : 0;
    const int og = act ? (tid % OPL) * OG : 0;

    half2v wrp[OG][3];
    float ber[OG], acc[OG];
#pragma unroll
    for (int k = 0; k < OG; k++) {
        acc[k] = 0.f;
        int j = i * COUT + og + k;
        if (act) {
            ber[k] = be[j];
#pragma unroll
            for (int t = 0; t < 3; t++)
                wrp[k][t] = bits_h2((int)pack_h2(We[(2 * t) * J + j], We[(2 * t + 1) * J + j]));
        } else {
            ber[k] = 0.f;
#pragma unroll
            for (int t = 0; t < 3; t++) wrp[k][t] = bits_h2(0);
        }
    }

    const int start = offs[n];
    const int end = offs[n + 1];
    const int len = end - start;
    const int per = (len + G - 1) / G;
    int p = start + g * per;
    int p1 = p + per;
    if (p1 > end) p1 = end;

    const float* hp_i = hprev + i;

    for (; p + U <= p1; p += U) {
        const int4* eb = ed4 + p;
        int4 ed[U];
#pragma unroll
        for (int u = 0; u < U; u++) ed[u] = eb[u];
        float xv[U];
#pragma unroll
        for (int u = 0; u < U; u++) xv[u] = hp_i[ed[u].w * CIN];
#pragma unroll
        for (int u = 0; u < U; u++) {
            half2v e01 = bits_h2(ed[u].x), e23 = bits_h2(ed[u].y), e45 = bits_h2(ed[u].z);
#pragma unroll
            for (int k = 0; k < OG; k++) {
                float z = FDOT2(e45, wrp[k][2],
                        FDOT2(e23, wrp[k][1],
                        FDOT2(e01, wrp[k][0], ber[k])));
                acc[k] = fmaf(xv[u], fmaxf(z, 0.f), acc[k]);
            }
        }
    }
    for (; p < p1; ++p) {
        int4 ed = ed4[p];
        float xv = hp_i[ed.w * CIN];
        half2v e01 = bits_h2(ed.x), e23 = bits_h2(ed.y), e45 = bits_h2(ed.z);
#pragma unroll
        for (int k = 0; k < OG; k++) {
            float z = FDOT2(e45, wrp[k][2],
                    FDOT2(e23, wrp[k][1],
                    FDOT2(e01, wrp[k][0], ber[k])));
            acc[k] = fmaf(xv, fmaxf(z, 0.f), acc[k]);
        }
    }

    if constexpr (CIN == 1) {
        if (act) atomicAdd(&agg[n * COUT + og], acc[0]);
    } else {
        __shared__ float lds_acc[J];
        if (act) {
#pragma unroll
            for (int k = 0; k < OG; k++) lds_acc[i * COUT + og + k] = acc[k];
        }
        __syncthreads();
        if (tid < COUT) {
            float sum = 0.f;
#pragma unroll
            for (int ii = 0; ii < CIN; ii++) sum += lds_acc[ii * COUT + tid];
            atomicAdd(&agg[n * COUT + tid], sum);
        }
    }
}

// ---------------------------------------------------------------------------
// Finalize: mean + root-weight + bias + relu.  PIN/POUT = row pitches.
// ---------------------------------------------------------------------------
template <int CIN, int COUT, int PIN, int POUT>
__global__ __launch_bounds__(64) void nnconv_fin(const float* __restrict__ agg,
                                                 const int* __restrict__ offs,
                                                 const float* __restrict__ hprev,
                                                 const float* __restrict__ root,
                                                 const float* __restrict__ bias,
                                                 float* __restrict__ hout) {
    int n = blockIdx.x;
    int t = threadIdx.x;
    if (t >= COUT) return;
    int cnt = offs[n + 1] - offs[n];
    float inv = 1.f / fmaxf((float)cnt, 1.f);
    float v = agg[n * COUT + t] * inv;
#pragma unroll
    for (int i = 0; i < CIN; i++) v = fmaf(hprev[n * PIN + i], root[i * COUT + t], v);
    v += bias[t];
    hout[n * POUT + t] = fmaxf(v, 0.f);
}

// ---------------------------------------------------------------------------
// CBT: out[i,j] = sum_k |h3[i,k] - h3[j,k]|, h3 is [512,5]
// ---------------------------------------------------------------------------
__global__ __launch_bounds__(256) void cbt_kernel(const float* __restrict__ h3,
                                                  float* __restrict__ out) {
    __shared__ float lh[N_NODES * 5];
    int tid = threadIdx.x;
    for (int idx = tid; idx < N_NODES * 5; idx += 256) lh[idx] = h3[idx];
    __syncthreads();
    int i = blockIdx.x;
    float hi[5];
#pragma unroll
    for (int k = 0; k < 5; k++) hi[k] = lh[i * 5 + k];
    for (int j = tid; j < N_NODES; j += 256) {
        float sacc = 0.f;
#pragma unroll
        for (int k = 0; k < 5; k++) sacc += fabsf(hi[k] - lh[j * 5 + k]);
        out[i * N_NODES + j] = sacc;
    }
}

// ---------------------------------------------------------------------------
extern "C" void kernel_launch(void* const* d_in, const int* in_sizes, int n_in,
                              void* d_out, int out_size, void* d_ws, size_t ws_size,
                              hipStream_t stream) {
    const float* x = (const float*)d_in[0];
    const float* edge_attr = (const float*)d_in[1];
    const int* edge_index = (const int*)d_in[2];
    const float* We1 = (const float*)d_in[3];
    const float* be1 = (const float*)d_in[4];
    const float* root1 = (const float*)d_in[5];
    const float* b1 = (const float*)d_in[6];
    const float* We2 = (const float*)d_in[7];
    const float* be2 = (const float*)d_in[8];
    const float* root2 = (const float*)d_in[9];
    const float* b2 = (const float*)d_in[10];
    const float* We3 = (const float*)d_in[11];
    const float* be3 = (const float*)d_in[12];
    const float* root3 = (const float*)d_in[13];
    const float* b3 = (const float*)d_in[14];

    const int E = N_EDGES;
    const int* src = edge_index;
    const int* dst = edge_index + E;

    char* ws = (char*)d_ws;
    int* offs = (int*)(ws + 0);                // 513 ints (pad to 4096)
    int* bcnt = (int*)(ws + 4096);             // 256*512 -> 528384
    int* base = (int*)(ws + 528384);           // 256*512 -> 1052672
    int4* ed4 = (int4*)(ws + 1052672);         // E*16B -> 5246976
    int4* edp = (int4*)(ws + 5246976);         // 512*768*32B -> 17829888
    int* srcp = (int*)(ws + 17829888);         // 512*768*4 -> 19402752
    int4* wtg = (int4*)(ws + 19402752);        // 864*32B -> 19430400
    float* agg1 = (float*)(ws + 19430400);     // 512*36 -> 19504128
    float* agg2 = (float*)(ws + 19504128);     // 512*24 -> 19553280
    float* agg3 = (float*)(ws + 19553280);     // 512*5  -> 19563520
    float* h1 = (float*)(ws + 19563520);       // 512*40 (pitch 40) -> 19645440
    float* h2 = (float*)(ws + 19645440);       // 512*24 -> 19694592
    float* h3 = (float*)(ws + 19694592);       // 512*5  -> 19704832

    const int aggn = N_NODES * (36 + 24 + 5);  // contiguous agg1|agg2|agg3

    hipMemsetAsync(edp, 0, (size_t)N_NODES * PADLEN * 32, stream);  // zero pad records

    count_kernel<<<NBLK, 256, 0, stream>>>(dst, bcnt, agg1, aggn);
    scan_kernel<<<1, 512, 0, stream>>>(bcnt, offs, base);
    scatter_kernel<<<NBLK, 256, 0, stream>>>(src, dst, edge_attr, base, offs, ed4, edp, srcp);
    wprep_kernel<<<4, 256, 0, stream>>>(We2, be2, wtg);

    // L1: CIN=1, COUT=36 (VALU) -> h1 pitch 40
    nnconv_edges<1, 36, 1, 64, 16><<<N_NODES * 16, 64, 0, stream>>>(x, ed4, offs, We1, be1, agg1);
    nnconv_fin<1, 36, 1, 40><<<N_NODES, 64, 0, stream>>>(agg1, offs, x, root1, b1, h1);

    // L2: MFMA edge pipeline
    nnconv2_mfma<<<N_NODES * 8 / 4, 256, 0, stream>>>(h1, (const char*)edp, srcp, wtg, agg2);
    nnconv_fin<36, 24, 40, 24><<<N_NODES, 64, 0, stream>>>(agg2, offs, h1, root2, b2, h2);

    // L3: CIN=24, COUT=5 (VALU)
    nnconv_edges<24, 5, 1, 128, 8><<<N_NODES * 8, 128, 0, stream>>>(h2, ed4, offs, We3, be3, agg3);
    nnconv_fin<24, 5, 24, 5><<<N_NODES, 64, 0, stream>>>(agg3, offs, h2, root3, b3, h3);

    cbt_kernel<<<N_NODES, 256, 0, stream>>>(h3, (float*)d_out);
}

// Round 8
// 220.172 us; speedup vs baseline: 5.2955x; 5.2955x over previous
//
#include <hip/hip_runtime.h>
#include <hip/hip_bf16.h>
#include <hip/hip_fp16.h>

#define N_NODES 512
#define N_EDGES (512 * 512)
#define NBLK 256                 // sort blocks
#define EPB (N_EDGES / NBLK)     // 1024 edges per sort block
#define PADLEN 768               // padded segment length (max cnt ~630 << 768)

typedef __attribute__((ext_vector_type(8))) __bf16 bf16x8;
typedef __attribute__((ext_vector_type(16))) float f32x16;

static __device__ inline unsigned bf16rne(float f) {
    union { float f; unsigned u; } c;
    c.f = f;
    unsigned u = c.u;
    u += 0x7FFFu + ((u >> 16) & 1u);
    return u >> 16;
}
static __device__ inline float bf2f(unsigned h) {
    union { unsigned u; float f; } c;
    c.u = h << 16;
    return c.f;
}

// ---------------------------------------------------------------------------
// Counting sort by dst — no device-scope atomics.
// ---------------------------------------------------------------------------
__global__ __launch_bounds__(256) void count_kernel(const int* __restrict__ dst,
                                                    int* __restrict__ bcnt) {
    __shared__ int h[N_NODES];
    int tid = threadIdx.x;
    int b = blockIdx.x;
    h[tid] = 0;
    h[tid + 256] = 0;
    __syncthreads();
#pragma unroll
    for (int k = 0; k < EPB / 256; k++)
        atomicAdd(&h[dst[b * EPB + k * 256 + tid]], 1);
    __syncthreads();
    bcnt[b * N_NODES + tid] = h[tid];
    bcnt[b * N_NODES + tid + 256] = h[tid + 256];
}

__global__ __launch_bounds__(512) void scan_kernel(const int* __restrict__ bcnt,
                                                   int* __restrict__ offs,
                                                   int* __restrict__ base) {
    __shared__ int buf[N_NODES];
    int t = threadIdx.x;
    int sum = 0;
#pragma unroll 16
    for (int b = 0; b < NBLK; b++) sum += bcnt[b * N_NODES + t];  // coalesced rows
    buf[t] = sum;
    __syncthreads();
    for (int d = 1; d < N_NODES; d <<= 1) {
        int add = (t >= d) ? buf[t - d] : 0;
        __syncthreads();
        buf[t] += add;
        __syncthreads();
    }
    offs[t + 1] = buf[t];
    if (t == 0) offs[0] = 0;
    int run = buf[t] - sum;  // exclusive global start of bucket t
#pragma unroll 16
    for (int b = 0; b < NBLK; b++) {
        base[b * N_NODES + t] = run;
        run += bcnt[b * N_NODES + t];
    }
}

// scatter: emit padded 32B bf16 A-record at dv*PADLEN+rank, plus src id.
// k-layout: {eh0..eh5, 1.0, eh0 | eh1..eh5, 1.0, 0, 0}  (k14,k15 = 0)
__global__ __launch_bounds__(256) void scatter_kernel(const int* __restrict__ src,
                                                      const int* __restrict__ dst,
                                                      const float* __restrict__ ea,
                                                      const int* __restrict__ base,
                                                      const int* __restrict__ offs,
                                                      int4* __restrict__ edp,
                                                      int* __restrict__ srcp) {
    __shared__ int lcur[N_NODES];
    __shared__ int loff[N_NODES];
    int tid = threadIdx.x;
    int b = blockIdx.x;
    lcur[tid] = base[b * N_NODES + tid];
    lcur[tid + 256] = base[b * N_NODES + tid + 256];
    loff[tid] = offs[tid];
    loff[tid + 256] = offs[tid + 256];
    __syncthreads();
    const unsigned ONE = 0x3F80u;  // 1.0 in bf16
#pragma unroll
    for (int k = 0; k < EPB / 256; k++) {
        int e = b * EPB + k * 256 + tid;
        const float* a = ea + (size_t)e * 6;
        unsigned e0 = bf16rne(a[0]), e1 = bf16rne(a[1]), e2 = bf16rne(a[2]);
        unsigned e3 = bf16rne(a[3]), e4 = bf16rne(a[4]), e5 = bf16rne(a[5]);
        int dv = dst[e], sv = src[e];
        int p = atomicAdd(&lcur[dv], 1);  // LDS atomic, compact slot
        int rank = p - loff[dv];
        size_t pi = (size_t)dv * PADLEN + rank;
        int4 r0, r1;
        r0.x = (int)((e1 << 16) | e0);
        r0.y = (int)((e3 << 16) | e2);
        r0.z = (int)((e5 << 16) | e4);
        r0.w = (int)((e0 << 16) | ONE);   // k6 = 1.0, k7 = eh0
        r1.x = (int)((e2 << 16) | e1);
        r1.y = (int)((e4 << 16) | e3);
        r1.z = (int)((ONE << 16) | e5);   // k12 = eh5, k13 = 1.0
        r1.w = 0;
        edp[pi * 2] = r0;
        edp[pi * 2 + 1] = r1;
        srcp[pi] = sv;
    }
}

// W prepack: per (tile t, lane): 8 bf16 = W~[k = hi*8 + 0..7][j = t*32+col].
// W~ rows: k0..5 = We_hi[v], k6 = be_hi, k7 = Wl0, k8..12 = Wl1..5,
//          k13 = be_lo, k14,15 = 0.  (hi/lo split makes eh*W + be exact)
__global__ __launch_bounds__(256) void wprep_kernel(const float* __restrict__ We,
                                                    const float* __restrict__ be,
                                                    int Jr, int total,
                                                    int4* __restrict__ wtg) {
    int idx = blockIdx.x * 256 + threadIdx.x;
    if (idx >= total) return;
    int t = idx >> 6, lane = idx & 63, col = lane & 31, hi = lane >> 5;
    int j = t * 32 + col;
    unsigned h[8] = {0, 0, 0, 0, 0, 0, 0, 0};
    if (j < Jr) {
        unsigned wh[6];
        float wl[6];
        for (int v = 0; v < 6; v++) {
            float wv = We[v * Jr + j];
            wh[v] = bf16rne(wv);
            wl[v] = wv - bf2f(wh[v]);
        }
        float bev = be[j];
        unsigned bh = bf16rne(bev);
        float bl = bev - bf2f(bh);
        if (hi == 0) {
            for (int v = 0; v < 6; v++) h[v] = wh[v];
            h[6] = bh;
            h[7] = bf16rne(wl[0]);
        } else {
            for (int v = 1; v < 6; v++) h[v - 1] = bf16rne(wl[v]);
            h[5] = bf16rne(bl);
            h[6] = 0;
            h[7] = 0;
        }
    }
    int4 r;
    r.x = (int)((h[1] << 16) | h[0]);
    r.y = (int)((h[3] << 16) | h[2]);
    r.z = (int)((h[5] << 16) | h[4]);
    r.w = (int)((h[7] << 16) | h[6]);
    wtg[idx] = r;
}

// ---------------------------------------------------------------------------
// Generic NNConv layer via MFMA. One block per node (512 thr = 8 waves x 3
// chunks x 32 edges = 768 padded slots). Per chunk: A-frag = 16B of the 32B
// edge record (lane: col=edge, hi=k-half); per tile: B-frag b128 from LDS,
// v_mfma_f32_32x32x16_bf16, epilogue relu * x (f16 from LDS) into per-slot
// scalar accumulators (slot = t % SLOTS, compile-time). Block epilogue: LDS
// float atomics -> mean + root + bias + relu -> hout. No spill surface:
// no stack arrays, no dynamic indexing, running pointers + imm offsets.
// ---------------------------------------------------------------------------
template <int CIN, int COUT, int TILES, int SLOTS>
__global__ __launch_bounds__(512, 4) void nnconv_mfma(
    const float* __restrict__ hprev,  // [512*CIN] f32
    const int4* __restrict__ edp,     // padded edge records
    const int* __restrict__ srcp,     // padded src ids
    const int* __restrict__ offs,     // [513]
    const int4* __restrict__ wtg,     // [TILES*64]
    const float* __restrict__ root,   // [CIN*COUT]
    const float* __restrict__ bias,   // [COUT]
    float* __restrict__ hout)         // [512*COUT]
{
    __shared__ __half xs[N_NODES * CIN];
    __shared__ int4 wl[TILES * 64];
    __shared__ float lagg[COUT];

    const int tid = threadIdx.x;
    const int n = blockIdx.x;

    for (int k = tid; k < N_NODES * CIN; k += 512) xs[k] = __float2half(hprev[k]);
    for (int k = tid; k < TILES * 64; k += 512) wl[k] = wtg[k];
    if (tid < COUT) lagg[tid] = 0.f;
    __syncthreads();

    const int w = tid >> 6, lane = tid & 63;
    const int col = lane & 31, hi = lane >> 5;
    const char* xsp = (const char*)xs;
    const char* wlp = (const char*)wl + (hi * 32 + col) * 16;

    f32x16 zc;
#pragma unroll
    for (int q = 0; q < 16; q++) zc[q] = 0.f;

    float ao[SLOTS];
#pragma unroll
    for (int s = 0; s < SLOTS; s++) ao[s] = 0.f;

    const int nb = n * PADLEN + w * 96;

    for (int c = 0; c < 3; c++) {
        const int cb = nb + c * 32;
        bf16x8 af = *(const bf16x8*)((const char*)edp + (size_t)(cb + col) * 32 + hi * 16);
        // srcs for this lane's 16 C-rows: row = (reg&3) + 8*(reg>>2) + 4*hi
        int xb[16];
#pragma unroll
        for (int qq = 0; qq < 4; qq++) {
            int4 sv = *(const int4*)(srcp + cb + qq * 8 + hi * 4);
            xb[qq * 4 + 0] = sv.x * (CIN * 2);
            xb[qq * 4 + 1] = sv.y * (CIN * 2);
            xb[qq * 4 + 2] = sv.z * (CIN * 2);
            xb[qq * 4 + 3] = sv.w * (CIN * 2);
        }
        const char* wq = wlp;
        int jb = col;
#pragma unroll 1
        for (int tt = 0; tt < TILES / SLOTS; tt++) {
#pragma unroll
            for (int s = 0; s < SLOTS; s++) {
                bf16x8 bf = *(const bf16x8*)(wq + s * 1024);
                f32x16 ct = __builtin_amdgcn_mfma_f32_32x32x16_bf16(af, bf, zc, 0, 0, 0);
                int j = jb + s * 32;
                int i = j / COUT;
                if (i > CIN - 1) i = CIN - 1;  // clamp for padded j (W row = 0 there)
                int i2 = i * 2;
#pragma unroll
                for (int r = 0; r < 16; r++) {
                    float xv = __half2float(*(const __half*)(xsp + xb[r] + i2));
                    ao[s] = fmaf(fmaxf(ct[r], 0.f), xv, ao[s]);
                }
            }
            wq += SLOTS * 1024;
            jb += SLOTS * 32;
        }
    }

#pragma unroll
    for (int s = 0; s < SLOTS; s++) {
        int o = (s * 32 + col) % COUT;  // pad j contribute exact 0
        atomicAdd(&lagg[o], ao[s]);
    }
    __syncthreads();

    if (tid < COUT) {
        int cnt = offs[n + 1] - offs[n];
        float v = lagg[tid] / fmaxf((float)cnt, 1.f);
#pragma unroll
        for (int i = 0; i < CIN; i++)
            v = fmaf(hprev[n * CIN + i], root[i * COUT + tid], v);
        hout[n * COUT + tid] = fmaxf(v + bias[tid], 0.f);
    }
}

// ---------------------------------------------------------------------------
// CBT: out[i,j] = sum_k |h3[i,k] - h3[j,k]|, h3 is [512,5]
// ---------------------------------------------------------------------------
__global__ __launch_bounds__(256) void cbt_kernel(const float* __restrict__ h3,
                                                  float* __restrict__ out) {
    __shared__ float lh[N_NODES * 5];
    int tid = threadIdx.x;
    for (int idx = tid; idx < N_NODES * 5; idx += 256) lh[idx] = h3[idx];
    __syncthreads();
    int i = blockIdx.x;
    float hi[5];
#pragma unroll
    for (int k = 0; k < 5; k++) hi[k] = lh[i * 5 + k];
    for (int j = tid; j < N_NODES; j += 256) {
        float sacc = 0.f;
#pragma unroll
        for (int k = 0; k < 5; k++) sacc += fabsf(hi[k] - lh[j * 5 + k]);
        out[i * N_NODES + j] = sacc;
    }
}

// ---------------------------------------------------------------------------
extern "C" void kernel_launch(void* const* d_in, const int* in_sizes, int n_in,
                              void* d_out, int out_size, void* d_ws, size_t ws_size,
                              hipStream_t stream) {
    const float* x = (const float*)d_in[0];
    const float* edge_attr = (const float*)d_in[1];
    const int* edge_index = (const int*)d_in[2];
    const float* We1 = (const float*)d_in[3];
    const float* be1 = (const float*)d_in[4];
    const float* root1 = (const float*)d_in[5];
    const float* b1 = (const float*)d_in[6];
    const float* We2 = (const float*)d_in[7];
    const float* be2 = (const float*)d_in[8];
    const float* root2 = (const float*)d_in[9];
    const float* b2 = (const float*)d_in[10];
    const float* We3 = (const float*)d_in[11];
    const float* be3 = (const float*)d_in[12];
    const float* root3 = (const float*)d_in[13];
    const float* b3 = (const float*)d_in[14];

    const int E = N_EDGES;
    const int* src = edge_index;
    const int* dst = edge_index + E;

    char* ws = (char*)d_ws;
    int* offs = (int*)(ws + 0);                // 513 ints (pad to 4096)
    int* bcnt = (int*)(ws + 4096);             // 256*512 -> 528384
    int* base = (int*)(ws + 528384);           // 256*512 -> 1052672
    int4* edp = (int4*)(ws + 1052672);         // 512*768*32B -> 13635584
    int* srcp = (int*)(ws + 13635584);         // 512*768*4  -> 15208448
    int4* wtg1 = (int4*)(ws + 15208448);       // 2*64*16  -> 15210496
    int4* wtg2 = (int4*)(ws + 15210496);       // 27*64*16 -> 15238144
    int4* wtg3 = (int4*)(ws + 15238144);       // 4*64*16  -> 15242240
    float* h1 = (float*)(ws + 15242240);       // 512*36 -> 15315968
    float* h2 = (float*)(ws + 15315968);       // 512*24 -> 15365120
    float* h3 = (float*)(ws + 15365120);       // 512*5  -> 15375360

    // zero pad records + pad srcs (edp and srcp contiguous)
    hipMemsetAsync(edp, 0, (size_t)N_NODES * PADLEN * 32 + (size_t)N_NODES * PADLEN * 4, stream);

    count_kernel<<<NBLK, 256, 0, stream>>>(dst, bcnt);
    scan_kernel<<<1, 512, 0, stream>>>(bcnt, offs, base);
    scatter_kernel<<<NBLK, 256, 0, stream>>>(src, dst, edge_attr, base, offs, edp, srcp);

    wprep_kernel<<<1, 256, 0, stream>>>(We1, be1, 36, 2 * 64, wtg1);
    wprep_kernel<<<7, 256, 0, stream>>>(We2, be2, 864, 27 * 64, wtg2);
    wprep_kernel<<<1, 256, 0, stream>>>(We3, be3, 120, 4 * 64, wtg3);

    // L1: CIN=1, COUT=36, J pad 36->64 (2 tiles)
    nnconv_mfma<1, 36, 2, 2><<<N_NODES, 512, 0, stream>>>(x, edp, srcp, offs, wtg1, root1, b1, h1);
    // L2: CIN=36, COUT=24, J=864 (27 tiles, slot period 3)
    nnconv_mfma<36, 24, 27, 3><<<N_NODES, 512, 0, stream>>>(h1, edp, srcp, offs, wtg2, root2, b2, h2);
    // L3: CIN=24, COUT=5, J pad 120->128 (4 tiles)
    nnconv_mfma<24, 5, 4, 4><<<N_NODES, 512, 0, stream>>>(h2, edp, srcp, offs, wtg3, root3, b3, h3);

    cbt_kernel<<<N_NODES, 256, 0, stream>>>(h3, (float*)d_out);
}